// Round 2
// baseline (457.453 us; speedup 1.0000x reference)
//
#include <hip/hip_runtime.h>

// ---------------- problem constants ----------------
#define BATCH   4
#define SEQ     2048
#define DMODEL  512
#define NHEADS  8
#define HEADDIM 64
#define MTOT    (BATCH*SEQ)      // 8192 rows
#define NX      (MTOT*DMODEL)    // 4194304 x elements
#define NW      (DMODEL*DMODEL)  // 262144 weight elements
// ---------------------------------------------------

typedef unsigned short u16;
typedef __bf16 bf16x8 __attribute__((ext_vector_type(8)));
typedef float  f32x4  __attribute__((ext_vector_type(4)));
typedef unsigned short u16x4 __attribute__((ext_vector_type(4)));

#define MFMA(a,b,c) __builtin_amdgcn_mfma_f32_16x16x32_bf16(a,b,c,0,0,0)

__device__ __forceinline__ u16 f2bf(float f) {
    unsigned u = __float_as_uint(f);
    u += 0x7FFFu + ((u >> 16) & 1u);   // round-to-nearest-even
    return (u16)(u >> 16);
}

__device__ __forceinline__ float qmax16(float v) {
    v = fmaxf(v, __shfl_xor(v, 1));
    v = fmaxf(v, __shfl_xor(v, 2));
    v = fmaxf(v, __shfl_xor(v, 4));
    v = fmaxf(v, __shfl_xor(v, 8));
    return v;
}
__device__ __forceinline__ float qsum16(float v) {
    v += __shfl_xor(v, 1);
    v += __shfl_xor(v, 2);
    v += __shfl_xor(v, 4);
    v += __shfl_xor(v, 8);
    return v;
}

// ---------------- kernel 0: fp32 -> bf16 converts + rope tables ----------------
// vec4 region: x (4M), Wq,Wk,Wv,Wo (256K each).  Tail: rope tables, 65536 entries.
#define NCVT4 ((NX + 4*NW)/4)    // 1310720 float4 groups
__global__ __launch_bounds__(256) void cvt_rope_kernel(
    const float* __restrict__ x,
    const float* __restrict__ wq, const float* __restrict__ wk,
    const float* __restrict__ wv, const float* __restrict__ wo,
    u16* __restrict__ xbf,
    u16* __restrict__ wqbf, u16* __restrict__ wkbf,
    u16* __restrict__ wvbf, u16* __restrict__ wobf,
    float* __restrict__ cos_t, float* __restrict__ sin_t)
{
    int i4 = blockIdx.x * 256 + threadIdx.x;
    if (i4 < NCVT4) {
        int i = i4 * 4;
        const float* s; u16* d; int o;
        if (i < NX) { s = x; d = xbf; o = i; }
        else {
            int j = i - NX;
            int r = j >> 18;            // NW = 2^18
            o = j & (NW - 1);
            s = (r == 0) ? wq : (r == 1) ? wk : (r == 2) ? wv : wo;
            d = (r == 0) ? wqbf : (r == 1) ? wkbf : (r == 2) ? wvbf : wobf;
        }
        float4 v = *(const float4*)(s + o);
        u16x4 u = { f2bf(v.x), f2bf(v.y), f2bf(v.z), f2bf(v.w) };
        *(u16x4*)(d + o) = u;
    } else {
        int r = i4 - NCVT4;             // [0, 16384)
        if (r < SEQ * 32 / 4) {
            int idx = r * 4;
            int s  = idx >> 5;
            int p0 = idx & 31;
#pragma unroll
            for (int t = 0; t < 4; ++t) {
                int p = p0 + t;
                // inv_freq = 10000^(-(p%16)/16) = exp(-ln(10000)/16 * (p%16))
                float inv = __expf(-0.5756462732485115f * (float)(p & 15));
                float ang = (float)s * inv;
                cos_t[idx + t] = cosf(ang);
                sin_t[idx + t] = sinf(ang);
            }
        }
    }
}

// ---------------- kernel 1: fused QKV projection + RoPE ----------------
// xbf:(8192,512) bf16.  W*bf:(512,512) bf16 row-major (out,in).  out = x @ W^T + b
// Q,K: rope applied, stored (B,H,S,64).  V: stored transposed (B,H,64,S).
__global__ __launch_bounds__(256) void qkv_kernel(
    const u16* __restrict__ x,
    const u16* __restrict__ Wq, const float* __restrict__ bq,
    const u16* __restrict__ Wk, const float* __restrict__ bk,
    const u16* __restrict__ Wv, const float* __restrict__ bv,
    const float* __restrict__ cos_t, const float* __restrict__ sin_t,
    u16* __restrict__ qws, u16* __restrict__ kws, u16* __restrict__ vtws)
{
    const int m0 = blockIdx.x * 64;          // row tile (128 tiles)
    const int n0 = blockIdx.y * 64;          // col tile over 1536 (24 tiles)
    const int tid  = threadIdx.x;
    const int w    = tid >> 6;
    const int lane = tid & 63;
    const int quad = lane >> 4;
    const int l16  = lane & 15;
    const int wm = w & 1, wn = w >> 1;

    const int sec = n0 >> 9;                 // 0=Q 1=K 2=V
    const int oc0 = n0 & 511;
    const u16*   Wm = (sec == 0) ? Wq : (sec == 1 ? Wk : Wv);
    const float* bb = (sec == 0) ? bq : (sec == 1 ? bk : bv);

    f32x4 acc[2][2] = {};
    const int ar = m0 + wm * 32 + l16;       // x row for A frags
    const int br = oc0 + wn * 32 + l16;      // W row (= output col)

#pragma unroll 4
    for (int k = 0; k < 512; k += 32) {
        const int ka = k + quad * 8;
        bf16x8 a0 = *(const bf16x8*)(x + ar * 512 + ka);
        bf16x8 a1 = *(const bf16x8*)(x + (ar + 16) * 512 + ka);
        bf16x8 b0 = *(const bf16x8*)(Wm + br * 512 + ka);
        bf16x8 b1 = *(const bf16x8*)(Wm + (br + 16) * 512 + ka);
        acc[0][0] = MFMA(a0, b0, acc[0][0]);
        acc[0][1] = MFMA(a0, b1, acc[0][1]);
        acc[1][0] = MFMA(a1, b0, acc[1][0]);
        acc[1][1] = MFMA(a1, b1, acc[1][1]);
    }

    // epilogue: bias (+ rope for Q/K), scatter to attention layouts
#pragma unroll
    for (int tm = 0; tm < 2; ++tm) {
#pragma unroll
        for (int tn = 0; tn < 2; ++tn) {
            const int col = oc0 + wn * 32 + tn * 16 + l16;   // [0,512)
            const int hh  = col >> 6;
            const int d   = col & 63;
            const float bval = bb[col];
#pragma unroll
            for (int r = 0; r < 4; ++r) {
                const int R = m0 + wm * 32 + tm * 16 + quad * 4 + r; // global row
                const int bi = R >> 11;       // batch
                const int s  = R & 2047;      // seq pos
                float val = acc[tm][tn][r] + bval;
                if (sec < 2) {
                    // rope: pairs are adjacent cols -> adjacent lanes
                    float other = __shfl_xor(val, 1);
                    const int p = d >> 1;
                    const float c  = cos_t[s * 32 + p];
                    const float sn = sin_t[s * 32 + p];
                    float res = ((d & 1) == 0) ? (val * c - other * sn)
                                               : (other * sn + val * c);
                    u16* dst = (sec == 0) ? qws : kws;
                    dst[((bi * NHEADS + hh) * SEQ + s) * HEADDIM + d] = f2bf(res);
                } else {
                    vtws[((bi * NHEADS + hh) * HEADDIM + d) * SEQ + s] = f2bf(val);
                }
            }
        }
    }
}

// ---------------- kernel 2: flash attention ----------------
// grid: (S/64 q-tiles, B*H).  block: 256 = 4 waves, each wave owns 16 q rows.
__global__ __launch_bounds__(256) void attn_kernel(
    const u16* __restrict__ qws, const u16* __restrict__ kws,
    const u16* __restrict__ vtws,
    const int* __restrict__ vids, const float* __restrict__ mask,
    const float* __restrict__ u_same, const float* __restrict__ u_cross,
    u16* __restrict__ attn)
{
    __shared__ alignas(16) u16 pls[4][16][64];   // per-wave P tile (C->A layout bounce)

    const int bh = blockIdx.y;
    const int b  = bh >> 3;
    const int h  = bh & 7;
    const int q0 = blockIdx.x * 64;

    const int tid  = threadIdx.x;
    const int w    = tid >> 6;
    const int lane = tid & 63;
    const int quad = lane >> 4;
    const int l16  = lane & 15;

    const float us = u_same[h];
    const float uc = u_cross[h];
    const int base = bh * (SEQ * HEADDIM);       // q/k base; also vt base

    // Q A-fragments (fixed for the whole block)
    const int qrow = q0 + w * 16 + l16;
    const bf16x8 aq0 = *(const bf16x8*)(qws + base + qrow * HEADDIM + quad * 8);
    const bf16x8 aq1 = *(const bf16x8*)(qws + base + qrow * HEADDIM + 32 + quad * 8);

    int vq[4];
#pragma unroll
    for (int r = 0; r < 4; ++r)
        vq[r] = vids[b * SEQ + q0 + w * 16 + quad * 4 + r];

    float mi[4], li[4];
    f32x4 o[4] = {};
#pragma unroll
    for (int r = 0; r < 4; ++r) { mi[r] = -1e30f; li[r] = 0.0f; }

    for (int kt = 0; kt < SEQ / 64; ++kt) {
        const int k0 = kt * 64;
        float sv[4][4];

        // ---- scores: QK^T * scale + bias + mask ----
#pragma unroll
        for (int nt = 0; nt < 4; ++nt) {
            const int krow = k0 + nt * 16 + l16;
            const bf16x8 b0 = *(const bf16x8*)(kws + base + krow * HEADDIM + quad * 8);
            const bf16x8 b1 = *(const bf16x8*)(kws + base + krow * HEADDIM + 32 + quad * 8);
            f32x4 sc = {};
            sc = MFMA(aq0, b0, sc);
            sc = MFMA(aq1, b1, sc);
            const int   vk   = vids[b * SEQ + krow];
            const float mk   = mask[b * SEQ + krow];
            const float madd = (1.0f - mk) * -1e9f;
#pragma unroll
            for (int r = 0; r < 4; ++r)
                sv[nt][r] = sc[r] * 0.125f + ((vk == vq[r]) ? us : uc) + madd;
        }

        // ---- online softmax (rows live inside a 16-lane quad) ----
#pragma unroll
        for (int r = 0; r < 4; ++r) {
            float rm = fmaxf(fmaxf(sv[0][r], sv[1][r]), fmaxf(sv[2][r], sv[3][r]));
            rm = qmax16(rm);
            const float nm    = fmaxf(mi[r], rm);
            const float alpha = __expf(mi[r] - nm);
            float rs = 0.0f;
#pragma unroll
            for (int nt = 0; nt < 4; ++nt) {
                const float p = __expf(sv[nt][r] - nm);
                sv[nt][r] = p;
                rs += p;
            }
            rs = qsum16(rs);
            li[r] = li[r] * alpha + rs;
            mi[r] = nm;
#pragma unroll
            for (int nt = 0; nt < 4; ++nt) o[nt][r] *= alpha;
        }

        // ---- P: C-layout -> LDS -> A-layout (bf16) ----
        __syncthreads();   // WAR guard vs previous iter's reads
#pragma unroll
        for (int nt = 0; nt < 4; ++nt)
#pragma unroll
            for (int r = 0; r < 4; ++r)
                pls[w][quad * 4 + r][nt * 16 + l16] = f2bf(sv[nt][r]);
        __syncthreads();
        const bf16x8 ap0 = *(const bf16x8*)(&pls[w][l16][quad * 8]);
        const bf16x8 ap1 = *(const bf16x8*)(&pls[w][l16][32 + quad * 8]);

        // ---- O += P @ V  (V stored transposed: (d, s)) ----
#pragma unroll
        for (int nt = 0; nt < 4; ++nt) {
            const u16* vb = vtws + base + (nt * 16 + l16) * SEQ + k0;
            const bf16x8 b0 = *(const bf16x8*)(vb + quad * 8);
            const bf16x8 b1 = *(const bf16x8*)(vb + 32 + quad * 8);
            o[nt] = MFMA(ap0, b0, o[nt]);
            o[nt] = MFMA(ap1, b1, o[nt]);
        }
    }

    // ---- epilogue: normalize, write (B,S,H*64) bf16 ----
#pragma unroll
    for (int r = 0; r < 4; ++r) {
        const float inv = 1.0f / li[r];
        const int R = q0 + w * 16 + quad * 4 + r;
        const int rowbase = (b * SEQ + R) * DMODEL + h * HEADDIM;
#pragma unroll
        for (int nt = 0; nt < 4; ++nt)
            attn[rowbase + nt * 16 + l16] = f2bf(o[nt][r] * inv);
    }
}

// ---------------- kernel 3: output projection (fp32 out) ----------------
__global__ __launch_bounds__(256) void proj_kernel(
    const u16* __restrict__ a, const u16* __restrict__ Wo,
    const float* __restrict__ bo, float* __restrict__ out)
{
    const int m0 = blockIdx.x * 64;
    const int n0 = blockIdx.y * 64;          // [0,512)
    const int tid  = threadIdx.x;
    const int w    = tid >> 6;
    const int lane = tid & 63;
    const int quad = lane >> 4;
    const int l16  = lane & 15;
    const int wm = w & 1, wn = w >> 1;

    f32x4 acc[2][2] = {};
    const int ar = m0 + wm * 32 + l16;
    const int br = n0 + wn * 32 + l16;

#pragma unroll 4
    for (int k = 0; k < 512; k += 32) {
        const int ka = k + quad * 8;
        bf16x8 a0 = *(const bf16x8*)(a + ar * 512 + ka);
        bf16x8 a1 = *(const bf16x8*)(a + (ar + 16) * 512 + ka);
        bf16x8 b0 = *(const bf16x8*)(Wo + br * 512 + ka);
        bf16x8 b1 = *(const bf16x8*)(Wo + (br + 16) * 512 + ka);
        acc[0][0] = MFMA(a0, b0, acc[0][0]);
        acc[0][1] = MFMA(a0, b1, acc[0][1]);
        acc[1][0] = MFMA(a1, b0, acc[1][0]);
        acc[1][1] = MFMA(a1, b1, acc[1][1]);
    }

#pragma unroll
    for (int tm = 0; tm < 2; ++tm) {
#pragma unroll
        for (int tn = 0; tn < 2; ++tn) {
            const int col = n0 + wn * 32 + tn * 16 + l16;
            const float bval = bo[col];
#pragma unroll
            for (int r = 0; r < 4; ++r) {
                const int R = m0 + wm * 32 + tm * 16 + quad * 4 + r;
                out[R * 512 + col] = acc[tm][tn][r] + bval;
            }
        }
    }
}

// ---------------- launch ----------------
extern "C" void kernel_launch(void* const* d_in, const int* in_sizes, int n_in,
                              void* d_out, int out_size, void* d_ws, size_t ws_size,
                              hipStream_t stream) {
    const float* x    = (const float*)d_in[0];
    const int*   vids = (const int*)d_in[1];
    const float* mask = (const float*)d_in[2];
    const float* Wq = (const float*)d_in[3];
    const float* bq = (const float*)d_in[4];
    const float* Wk = (const float*)d_in[5];
    const float* bk = (const float*)d_in[6];
    const float* Wv = (const float*)d_in[7];
    const float* bv = (const float*)d_in[8];
    const float* Wo = (const float*)d_in[9];
    const float* bo = (const float*)d_in[10];
    const float* usame  = (const float*)d_in[11];
    const float* ucross = (const float*)d_in[12];
    float* out = (float*)d_out;

    // workspace layout (34.5 MB total)
    u16* xbf  = (u16*)d_ws;                 // 8 MB; reused as attention output
    u16* wqbf = xbf + NX;                   // 512 KB each
    u16* wkbf = wqbf + NW;
    u16* wvbf = wkbf + NW;
    u16* wobf = wvbf + NW;
    float* cos_t = (float*)(wobf + NW);     // 256 KB
    float* sin_t = cos_t + SEQ * 32;        // 256 KB
    u16* qws  = (u16*)(sin_t + SEQ * 32);   // 8 MB each
    u16* kws  = qws + (size_t)BATCH * NHEADS * SEQ * HEADDIM;
    u16* vtws = kws + (size_t)BATCH * NHEADS * SEQ * HEADDIM;
    u16* attn = xbf;   // reuse: qkv_kernel has finished with xbf before attn writes

    // 1310720 cvt groups + 16384 rope groups = 1327104 threads = 5184 blocks
    cvt_rope_kernel<<<(NCVT4 + SEQ * 32 / 4 + 255) / 256, 256, 0, stream>>>(
        x, Wq, Wk, Wv, Wo, xbf, wqbf, wkbf, wvbf, wobf, cos_t, sin_t);

    dim3 g1(MTOT / 64, 3 * DMODEL / 64);   // 128 x 24
    qkv_kernel<<<g1, 256, 0, stream>>>(xbf, wqbf, bq, wkbf, bk, wvbf, bv,
                                       cos_t, sin_t, qws, kws, vtws);

    dim3 g2(SEQ / 64, BATCH * NHEADS);     // 32 x 32
    attn_kernel<<<g2, 256, 0, stream>>>(qws, kws, vtws, vids, mask,
                                        usame, ucross, attn);

    dim3 g3(MTOT / 64, DMODEL / 64);       // 128 x 8
    proj_kernel<<<g3, 256, 0, stream>>>(attn, wobf, bo, out);
}

// Round 3
// 336.198 us; speedup vs baseline: 1.3607x; 1.3607x over previous
//
#include <hip/hip_runtime.h>

// ---------------- problem constants ----------------
#define BATCH   4
#define SEQ     2048
#define DMODEL  512
#define NHEADS  8
#define HEADDIM 64
#define MTOT    (BATCH*SEQ)      // 8192 rows
#define NX      (MTOT*DMODEL)    // 4194304 x elements
#define NW      (DMODEL*DMODEL)  // 262144 weight elements
#define QTILE   128
#define KTILE   64
#define NKT     (SEQ/KTILE)      // 32
// ---------------------------------------------------

typedef unsigned short u16;
typedef __bf16 bf16x8 __attribute__((ext_vector_type(8)));
typedef float  f32x4  __attribute__((ext_vector_type(4)));
typedef unsigned short u16x4 __attribute__((ext_vector_type(4)));

#define MFMA(a,b,c) __builtin_amdgcn_mfma_f32_16x16x32_bf16(a,b,c,0,0,0)

__device__ __forceinline__ u16 f2bf(float f) {
    unsigned u = __float_as_uint(f);
    u += 0x7FFFu + ((u >> 16) & 1u);   // round-to-nearest-even
    return (u16)(u >> 16);
}

__device__ __forceinline__ float qmax16(float v) {
    v = fmaxf(v, __shfl_xor(v, 1));
    v = fmaxf(v, __shfl_xor(v, 2));
    v = fmaxf(v, __shfl_xor(v, 4));
    v = fmaxf(v, __shfl_xor(v, 8));
    return v;
}
__device__ __forceinline__ float qsum16(float v) {
    v += __shfl_xor(v, 1);
    v += __shfl_xor(v, 2);
    v += __shfl_xor(v, 4);
    v += __shfl_xor(v, 8);
    return v;
}

// async global->LDS (wave-uniform LDS base + lane*size)
__device__ __forceinline__ void gll16(const void* g, void* l) {
    __builtin_amdgcn_global_load_lds((const __attribute__((address_space(1))) void*)g,
                                     (__attribute__((address_space(3))) void*)l, 16, 0, 0);
}
__device__ __forceinline__ void gll4(const void* g, void* l) {
    __builtin_amdgcn_global_load_lds((const __attribute__((address_space(1))) void*)g,
                                     (__attribute__((address_space(3))) void*)l, 4, 0, 0);
}

// ---------------- kernel 0: fp32 -> bf16 converts + rope tables ----------------
#define NCVT4 ((NX + 4*NW)/4)    // 1310720 float4 groups
__global__ __launch_bounds__(256) void cvt_rope_kernel(
    const float* __restrict__ x,
    const float* __restrict__ wq, const float* __restrict__ wk,
    const float* __restrict__ wv, const float* __restrict__ wo,
    u16* __restrict__ xbf,
    u16* __restrict__ wqbf, u16* __restrict__ wkbf,
    u16* __restrict__ wvbf, u16* __restrict__ wobf,
    float* __restrict__ cos_t, float* __restrict__ sin_t)
{
    int i4 = blockIdx.x * 256 + threadIdx.x;
    if (i4 < NCVT4) {
        int i = i4 * 4;
        const float* s; u16* d; int o;
        if (i < NX) { s = x; d = xbf; o = i; }
        else {
            int j = i - NX;
            int r = j >> 18;            // NW = 2^18
            o = j & (NW - 1);
            s = (r == 0) ? wq : (r == 1) ? wk : (r == 2) ? wv : wo;
            d = (r == 0) ? wqbf : (r == 1) ? wkbf : (r == 2) ? wvbf : wobf;
        }
        float4 v = *(const float4*)(s + o);
        u16x4 u = { f2bf(v.x), f2bf(v.y), f2bf(v.z), f2bf(v.w) };
        *(u16x4*)(d + o) = u;
    } else {
        int r = i4 - NCVT4;             // [0, 16384)
        if (r < SEQ * 32 / 4) {
            int idx = r * 4;
            int s  = idx >> 5;
            int p0 = idx & 31;
#pragma unroll
            for (int t = 0; t < 4; ++t) {
                int p = p0 + t;
                float inv = __expf(-0.5756462732485115f * (float)(p & 15));
                float ang = (float)s * inv;
                cos_t[idx + t] = cosf(ang);
                sin_t[idx + t] = sinf(ang);
            }
        }
    }
}

// ---------------- kernel 1: fused QKV projection + RoPE ----------------
// Q: rope, linear (bh, s, d).
// K: rope, tiled-swizzled: tile (bh,kt) 64x64, elem (sr,d) at
//    tile*4096 + sr*64 + ((d>>3 ^ (sr&7))<<3) + (d&7)
// V: transposed tiled-swizzled: elem (d, sc) at
//    tile*4096 + d*64 + ((sc>>3 ^ (d&7))<<3) + (sc&7)
__global__ __launch_bounds__(256) void qkv_kernel(
    const u16* __restrict__ x,
    const u16* __restrict__ Wq, const float* __restrict__ bq,
    const u16* __restrict__ Wk, const float* __restrict__ bk,
    const u16* __restrict__ Wv, const float* __restrict__ bv,
    const float* __restrict__ cos_t, const float* __restrict__ sin_t,
    u16* __restrict__ qws, u16* __restrict__ kws, u16* __restrict__ vtws)
{
    const int m0 = blockIdx.x * 64;          // row tile (128 tiles)
    const int n0 = blockIdx.y * 64;          // col tile over 1536 (24 tiles)
    const int tid  = threadIdx.x;
    const int w    = tid >> 6;
    const int lane = tid & 63;
    const int quad = lane >> 4;
    const int l16  = lane & 15;
    const int wm = w & 1, wn = w >> 1;

    const int sec = n0 >> 9;                 // 0=Q 1=K 2=V
    const int oc0 = n0 & 511;
    const u16*   Wm = (sec == 0) ? Wq : (sec == 1 ? Wk : Wv);
    const float* bb = (sec == 0) ? bq : (sec == 1 ? bk : bv);

    f32x4 acc[2][2] = {};
    const int ar = m0 + wm * 32 + l16;       // x row for A frags
    const int br = oc0 + wn * 32 + l16;      // W row (= output col)

#pragma unroll 4
    for (int k = 0; k < 512; k += 32) {
        const int ka = k + quad * 8;
        bf16x8 a0 = *(const bf16x8*)(x + ar * 512 + ka);
        bf16x8 a1 = *(const bf16x8*)(x + (ar + 16) * 512 + ka);
        bf16x8 b0 = *(const bf16x8*)(Wm + br * 512 + ka);
        bf16x8 b1 = *(const bf16x8*)(Wm + (br + 16) * 512 + ka);
        acc[0][0] = MFMA(a0, b0, acc[0][0]);
        acc[0][1] = MFMA(a0, b1, acc[0][1]);
        acc[1][0] = MFMA(a1, b0, acc[1][0]);
        acc[1][1] = MFMA(a1, b1, acc[1][1]);
    }

#pragma unroll
    for (int tm = 0; tm < 2; ++tm) {
#pragma unroll
        for (int tn = 0; tn < 2; ++tn) {
            const int col = oc0 + wn * 32 + tn * 16 + l16;   // [0,512)
            const int hh  = col >> 6;
            const int d   = col & 63;
            const float bval = bb[col];
#pragma unroll
            for (int r = 0; r < 4; ++r) {
                const int R = m0 + wm * 32 + tm * 16 + quad * 4 + r; // global row
                const int bi = R >> 11;       // batch
                const int s  = R & 2047;      // seq pos
                const size_t hb = (size_t)(bi * NHEADS + hh) * (SEQ * HEADDIM);
                float val = acc[tm][tn][r] + bval;
                if (sec < 2) {
                    // rope: pairs are adjacent cols -> adjacent lanes
                    float other = __shfl_xor(val, 1);
                    const int p = d >> 1;
                    const float c  = cos_t[s * 32 + p];
                    const float sn = sin_t[s * 32 + p];
                    float res = ((d & 1) == 0) ? (val * c - other * sn)
                                               : (other * sn + val * c);
                    if (sec == 0) {
                        qws[hb + s * HEADDIM + d] = f2bf(res);
                    } else {
                        const int kt = s >> 6, sr = s & 63;
                        kws[hb + ((kt * 64 + sr) << 6)
                               + ((((d >> 3) ^ (sr & 7)) << 3) + (d & 7))] = f2bf(res);
                    }
                } else {
                    const int kt = s >> 6, sc = s & 63;
                    vtws[hb + ((kt * 64 + d) << 6)
                            + ((((sc >> 3) ^ (d & 7)) << 3) + (sc & 7))] = f2bf(val);
                }
            }
        }
    }
}

// ---------------- kernel 2: flash attention, LDS-staged, double-buffered ----------------
// grid: (SEQ/QTILE, B*H) = (16, 32). block 256 = 4 waves; each wave owns 32 q rows
// (two 16-row m-subtiles at q0 + s*64 + w*16).
__global__ __launch_bounds__(256) void attn_kernel(
    const u16* __restrict__ qws, const u16* __restrict__ ktl,
    const u16* __restrict__ vtl,
    const int* __restrict__ vids, const float* __restrict__ mask,
    const float* __restrict__ u_same, const float* __restrict__ u_cross,
    u16* __restrict__ attn)
{
    __shared__ alignas(16) u16 kbuf[2][KTILE * 64];   // 8 KB each, swizzled tiles
    __shared__ alignas(16) u16 vbuf[2][KTILE * 64];
    __shared__ alignas(16) u16 pls[4][32][72];        // per-wave P tile, padded (144B stride)
    __shared__ int   bid[2][KTILE];
    __shared__ float bmk[2][KTILE];

    const int bh = blockIdx.y;
    const int b  = bh >> 3;
    const int h  = bh & 7;
    const int q0 = blockIdx.x * QTILE;

    const int tid  = threadIdx.x;
    const int w    = tid >> 6;
    const int lane = tid & 63;
    const int quad = lane >> 4;
    const int l16  = lane & 15;

    const float us = u_same[h];
    const float uc = u_cross[h];
    const size_t tb = (size_t)bh * (SEQ * HEADDIM);

    // Q A-fragments (fixed for the whole block)
    bf16x8 aq[2][2];
#pragma unroll
    for (int s = 0; s < 2; ++s) {
        const int qr = q0 + s * 64 + w * 16 + l16;
        aq[s][0] = *(const bf16x8*)(qws + tb + qr * HEADDIM + quad * 8);
        aq[s][1] = *(const bf16x8*)(qws + tb + qr * HEADDIM + 32 + quad * 8);
    }
    int vq[2][4];
#pragma unroll
    for (int s = 0; s < 2; ++s)
#pragma unroll
        for (int r = 0; r < 4; ++r)
            vq[s][r] = vids[b * SEQ + q0 + s * 64 + w * 16 + quad * 4 + r];

    float mi[2][4], li[2][4];
    f32x4 o[2][4] = {};
#pragma unroll
    for (int s = 0; s < 2; ++s)
#pragma unroll
        for (int r = 0; r < 4; ++r) { mi[s][r] = -1e30f; li[s][r] = 0.0f; }

    auto stage = [&](int kt, int nb) {
        const u16* kg = ktl + tb + (size_t)kt * (KTILE * 64);
        const u16* vg = vtl + tb + (size_t)kt * (KTILE * 64);
        const int off = w * 1024;            // elements; wave covers 2 KB of the 8 KB tile
        gll16(kg + off +       lane * 8, &kbuf[nb][off]);
        gll16(kg + off + 512 + lane * 8, &kbuf[nb][off + 512]);
        gll16(vg + off +       lane * 8, &vbuf[nb][off]);
        gll16(vg + off + 512 + lane * 8, &vbuf[nb][off + 512]);
        if (w == 0) {
            gll4(vids + b * SEQ + kt * KTILE + lane, &bid[nb][0]);
            gll4(mask + b * SEQ + kt * KTILE + lane, &bmk[nb][0]);
        }
    };

    stage(0, 0);

    for (int kt = 0; kt < NKT; ++kt) {
        const int cur = kt & 1;
        __syncthreads();                    // drains vmcnt: tile cur ready; prev compute done
        if (kt + 1 < NKT) stage(kt + 1, cur ^ 1);

        float sv[2][4][4];

        // ---- scores: QK^T * scale + bias + mask ----
#pragma unroll
        for (int nt = 0; nt < 4; ++nt) {
            const int krow = nt * 16 + l16;
            const int r7   = krow & 7;
            const bf16x8 kb0 = *(const bf16x8*)&kbuf[cur][krow * 64 + (((quad ^ r7)) << 3)];
            const bf16x8 kb1 = *(const bf16x8*)&kbuf[cur][krow * 64 + (((quad ^ r7 ^ 4)) << 3)];
            const int   kv = bid[cur][krow];                 // col idx == krow expr
            const float md = (1.0f - bmk[cur][krow]) * -1e9f;
#pragma unroll
            for (int s = 0; s < 2; ++s) {
                f32x4 sc = {};
                sc = MFMA(aq[s][0], kb0, sc);
                sc = MFMA(aq[s][1], kb1, sc);
#pragma unroll
                for (int r = 0; r < 4; ++r)
                    sv[s][nt][r] = sc[r] * 0.125f + ((kv == vq[s][r]) ? us : uc) + md;
            }
        }

        // ---- online softmax (rows live inside a 16-lane quad) ----
#pragma unroll
        for (int s = 0; s < 2; ++s)
#pragma unroll
            for (int r = 0; r < 4; ++r) {
                float rm = fmaxf(fmaxf(sv[s][0][r], sv[s][1][r]),
                                 fmaxf(sv[s][2][r], sv[s][3][r]));
                rm = qmax16(rm);
                const float nm    = fmaxf(mi[s][r], rm);
                const float alpha = __expf(mi[s][r] - nm);
                float rs = 0.0f;
#pragma unroll
                for (int nt = 0; nt < 4; ++nt) {
                    const float p = __expf(sv[s][nt][r] - nm);
                    sv[s][nt][r] = p;
                    rs += p;
                }
                rs = qsum16(rs);
                li[s][r] = li[s][r] * alpha + rs;
                mi[s][r] = nm;
#pragma unroll
                for (int nt = 0; nt < 4; ++nt) o[s][nt][r] *= alpha;
            }

        // ---- P: C-layout -> per-wave LDS -> A-layout (no barrier needed) ----
#pragma unroll
        for (int s = 0; s < 2; ++s)
#pragma unroll
            for (int nt = 0; nt < 4; ++nt)
#pragma unroll
                for (int r = 0; r < 4; ++r)
                    pls[w][s * 16 + quad * 4 + r][nt * 16 + l16] = f2bf(sv[s][nt][r]);

        bf16x8 ap[2][2];
#pragma unroll
        for (int s = 0; s < 2; ++s) {
            ap[s][0] = *(const bf16x8*)&pls[w][s * 16 + l16][quad * 8];
            ap[s][1] = *(const bf16x8*)&pls[w][s * 16 + l16][32 + quad * 8];
        }

        // ---- O += P @ V ----
#pragma unroll
        for (int nt = 0; nt < 4; ++nt) {
            const int vrow = nt * 16 + l16;
            const int r7   = vrow & 7;
            const bf16x8 vb0 = *(const bf16x8*)&vbuf[cur][vrow * 64 + (((quad ^ r7)) << 3)];
            const bf16x8 vb1 = *(const bf16x8*)&vbuf[cur][vrow * 64 + (((quad ^ r7 ^ 4)) << 3)];
#pragma unroll
            for (int s = 0; s < 2; ++s) {
                o[s][nt] = MFMA(ap[s][0], vb0, o[s][nt]);
                o[s][nt] = MFMA(ap[s][1], vb1, o[s][nt]);
            }
        }
    }

    // ---- epilogue: normalize, write (B,S,H*64) bf16 ----
#pragma unroll
    for (int s = 0; s < 2; ++s)
#pragma unroll
        for (int r = 0; r < 4; ++r) {
            const float inv = 1.0f / li[s][r];
            const int R = q0 + s * 64 + w * 16 + quad * 4 + r;
            const int rb = (b * SEQ + R) * DMODEL + h * HEADDIM;
#pragma unroll
            for (int nt = 0; nt < 4; ++nt)
                attn[rb + nt * 16 + l16] = f2bf(o[s][nt][r] * inv);
        }
}

// ---------------- kernel 3: output projection (fp32 out) ----------------
__global__ __launch_bounds__(256) void proj_kernel(
    const u16* __restrict__ a, const u16* __restrict__ Wo,
    const float* __restrict__ bo, float* __restrict__ out)
{
    const int m0 = blockIdx.x * 64;
    const int n0 = blockIdx.y * 64;          // [0,512)
    const int tid  = threadIdx.x;
    const int w    = tid >> 6;
    const int lane = tid & 63;
    const int quad = lane >> 4;
    const int l16  = lane & 15;
    const int wm = w & 1, wn = w >> 1;

    f32x4 acc[2][2] = {};
    const int ar = m0 + wm * 32 + l16;
    const int br = n0 + wn * 32 + l16;

#pragma unroll 4
    for (int k = 0; k < 512; k += 32) {
        const int ka = k + quad * 8;
        bf16x8 a0 = *(const bf16x8*)(a + ar * 512 + ka);
        bf16x8 a1 = *(const bf16x8*)(a + (ar + 16) * 512 + ka);
        bf16x8 b0 = *(const bf16x8*)(Wo + br * 512 + ka);
        bf16x8 b1 = *(const bf16x8*)(Wo + (br + 16) * 512 + ka);
        acc[0][0] = MFMA(a0, b0, acc[0][0]);
        acc[0][1] = MFMA(a0, b1, acc[0][1]);
        acc[1][0] = MFMA(a1, b0, acc[1][0]);
        acc[1][1] = MFMA(a1, b1, acc[1][1]);
    }

#pragma unroll
    for (int tm = 0; tm < 2; ++tm) {
#pragma unroll
        for (int tn = 0; tn < 2; ++tn) {
            const int col = n0 + wn * 32 + tn * 16 + l16;
            const float bval = bo[col];
#pragma unroll
            for (int r = 0; r < 4; ++r) {
                const int R = m0 + wm * 32 + tm * 16 + quad * 4 + r;
                out[R * 512 + col] = acc[tm][tn][r] + bval;
            }
        }
    }
}

// ---------------- launch ----------------
extern "C" void kernel_launch(void* const* d_in, const int* in_sizes, int n_in,
                              void* d_out, int out_size, void* d_ws, size_t ws_size,
                              hipStream_t stream) {
    const float* x    = (const float*)d_in[0];
    const int*   vids = (const int*)d_in[1];
    const float* mask = (const float*)d_in[2];
    const float* Wq = (const float*)d_in[3];
    const float* bq = (const float*)d_in[4];
    const float* Wk = (const float*)d_in[5];
    const float* bk = (const float*)d_in[6];
    const float* Wv = (const float*)d_in[7];
    const float* bv = (const float*)d_in[8];
    const float* Wo = (const float*)d_in[9];
    const float* bo = (const float*)d_in[10];
    const float* usame  = (const float*)d_in[11];
    const float* ucross = (const float*)d_in[12];
    float* out = (float*)d_out;

    // workspace layout (34.5 MB total)
    u16* xbf  = (u16*)d_ws;                 // 8 MB; reused as attention output
    u16* wqbf = xbf + NX;                   // 512 KB each
    u16* wkbf = wqbf + NW;
    u16* wvbf = wkbf + NW;
    u16* wobf = wvbf + NW;
    float* cos_t = (float*)(wobf + NW);     // 256 KB
    float* sin_t = cos_t + SEQ * 32;        // 256 KB
    u16* qws  = (u16*)(sin_t + SEQ * 32);   // 8 MB each
    u16* kws  = qws + (size_t)BATCH * NHEADS * SEQ * HEADDIM;
    u16* vtws = kws + (size_t)BATCH * NHEADS * SEQ * HEADDIM;
    u16* attn = xbf;   // reuse: qkv_kernel has finished with xbf before attn writes

    cvt_rope_kernel<<<(NCVT4 + SEQ * 32 / 4 + 255) / 256, 256, 0, stream>>>(
        x, Wq, Wk, Wv, Wo, xbf, wqbf, wkbf, wvbf, wobf, cos_t, sin_t);

    dim3 g1(MTOT / 64, 3 * DMODEL / 64);   // 128 x 24
    qkv_kernel<<<g1, 256, 0, stream>>>(xbf, wqbf, bq, wkbf, bk, wvbf, bv,
                                       cos_t, sin_t, qws, kws, vtws);

    dim3 g2(SEQ / QTILE, BATCH * NHEADS);  // 16 x 32
    attn_kernel<<<g2, 256, 0, stream>>>(qws, kws, vtws, vids, mask,
                                        usame, ucross, attn);

    dim3 g3(MTOT / 64, DMODEL / 64);       // 128 x 8
    proj_kernel<<<g3, 256, 0, stream>>>(attn, wobf, bo, out);
}

// Round 4
// 286.423 us; speedup vs baseline: 1.5971x; 1.1738x over previous
//
#include <hip/hip_runtime.h>

// ---------------- problem constants ----------------
#define BATCH   4
#define SEQ     2048
#define DMODEL  512
#define NHEADS  8
#define HEADDIM 64
#define MTOT    (BATCH*SEQ)      // 8192 rows
#define NX      (MTOT*DMODEL)    // 4194304 x elements
#define NW      (DMODEL*DMODEL)  // 262144 weight elements
#define QTILE   128
#define KTILE   64
#define NKT     (SEQ/KTILE)      // 32
// ---------------------------------------------------

typedef unsigned short u16;
typedef __bf16 bf16x8 __attribute__((ext_vector_type(8)));
typedef float  f32x4  __attribute__((ext_vector_type(4)));
typedef unsigned short u16x4 __attribute__((ext_vector_type(4)));

#define MFMA(a,b,c) __builtin_amdgcn_mfma_f32_16x16x32_bf16(a,b,c,0,0,0)

__device__ __forceinline__ u16 f2bf(float f) {
    unsigned u = __float_as_uint(f);
    u += 0x7FFFu + ((u >> 16) & 1u);   // round-to-nearest-even
    return (u16)(u >> 16);
}

__device__ __forceinline__ float qmax16(float v) {
    v = fmaxf(v, __shfl_xor(v, 1));
    v = fmaxf(v, __shfl_xor(v, 2));
    v = fmaxf(v, __shfl_xor(v, 4));
    v = fmaxf(v, __shfl_xor(v, 8));
    return v;
}
__device__ __forceinline__ float qsum16(float v) {
    v += __shfl_xor(v, 1);
    v += __shfl_xor(v, 2);
    v += __shfl_xor(v, 4);
    v += __shfl_xor(v, 8);
    return v;
}

// async global->LDS (wave-uniform LDS base + lane*size)
__device__ __forceinline__ void gll16(const void* g, void* l) {
    __builtin_amdgcn_global_load_lds((const __attribute__((address_space(1))) void*)g,
                                     (__attribute__((address_space(3))) void*)l, 16, 0, 0);
}
__device__ __forceinline__ void gll4(const void* g, void* l) {
    __builtin_amdgcn_global_load_lds((const __attribute__((address_space(1))) void*)g,
                                     (__attribute__((address_space(3))) void*)l, 4, 0, 0);
}

// ---------------- kernel 0: fp32 -> bf16 converts + rope tables ----------------
#define NCVT4 ((NX + 4*NW)/4)    // 1310720 float4 groups
__global__ __launch_bounds__(256) void cvt_rope_kernel(
    const float* __restrict__ x,
    const float* __restrict__ wq, const float* __restrict__ wk,
    const float* __restrict__ wv, const float* __restrict__ wo,
    u16* __restrict__ xbf,
    u16* __restrict__ wqbf, u16* __restrict__ wkbf,
    u16* __restrict__ wvbf, u16* __restrict__ wobf,
    float* __restrict__ cos_t, float* __restrict__ sin_t)
{
    int i4 = blockIdx.x * 256 + threadIdx.x;
    if (i4 < NCVT4) {
        int i = i4 * 4;
        const float* s; u16* d; int o;
        if (i < NX) { s = x; d = xbf; o = i; }
        else {
            int j = i - NX;
            int r = j >> 18;            // NW = 2^18
            o = j & (NW - 1);
            s = (r == 0) ? wq : (r == 1) ? wk : (r == 2) ? wv : wo;
            d = (r == 0) ? wqbf : (r == 1) ? wkbf : (r == 2) ? wvbf : wobf;
        }
        float4 v = *(const float4*)(s + o);
        u16x4 u = { f2bf(v.x), f2bf(v.y), f2bf(v.z), f2bf(v.w) };
        *(u16x4*)(d + o) = u;
    } else {
        int r = i4 - NCVT4;             // [0, 16384)
        if (r < SEQ * 32 / 4) {
            int idx = r * 4;
            int s  = idx >> 5;
            int p0 = idx & 31;
#pragma unroll
            for (int t = 0; t < 4; ++t) {
                int p = p0 + t;
                float inv = __expf(-0.5756462732485115f * (float)(p & 15));
                float ang = (float)s * inv;
                cos_t[idx + t] = cosf(ang);
                sin_t[idx + t] = sinf(ang);
            }
        }
    }
}

// ---------------- kernel 1: fused QKV projection + RoPE (128x128 tiles) ----------------
// Q: rope, linear (bh, s, d).
// K: rope, tiled-swizzled: tile (bh,kt) 64x64, elem (sr,d) at
//    tile*4096 + sr*64 + ((d>>3 ^ (sr&7))<<3) + (d&7)
// V: transposed tiled-swizzled: elem (d, sc) at
//    tile*4096 + d*64 + ((sc>>3 ^ (d&7))<<3) + (sc&7)
__global__ __launch_bounds__(256) void qkv_kernel(
    const u16* __restrict__ x,
    const u16* __restrict__ Wq, const float* __restrict__ bq,
    const u16* __restrict__ Wk, const float* __restrict__ bk,
    const u16* __restrict__ Wv, const float* __restrict__ bv,
    const float* __restrict__ cos_t, const float* __restrict__ sin_t,
    u16* __restrict__ qws, u16* __restrict__ kws, u16* __restrict__ vtws)
{
    const int m0 = blockIdx.x * 128;         // row tile (64 tiles)
    const int n0 = blockIdx.y * 128;         // col tile over 1536 (12 tiles)
    const int tid  = threadIdx.x;
    const int w    = tid >> 6;
    const int lane = tid & 63;
    const int quad = lane >> 4;
    const int l16  = lane & 15;
    const int wm = w & 1, wn = w >> 1;       // 2x2 wave grid, each wave 64x64

    const int sec = n0 >> 9;                 // 0=Q 1=K 2=V
    const int oc0 = n0 & 511;
    const u16*   Wm = (sec == 0) ? Wq : (sec == 1 ? Wk : Wv);
    const float* bb = (sec == 0) ? bq : (sec == 1 ? bk : bv);

    f32x4 acc[4][4] = {};
    const int ar0 = m0 + wm * 64 + l16;      // x row base for A frags
    const int br0 = oc0 + wn * 64 + l16;     // W row base (= output col)

#pragma unroll 2
    for (int k = 0; k < 512; k += 32) {
        const int ka = k + quad * 8;
        bf16x8 a[4], bfr[4];
#pragma unroll
        for (int t = 0; t < 4; ++t) {
            a[t]   = *(const bf16x8*)(x  + (ar0 + t * 16) * 512 + ka);
            bfr[t] = *(const bf16x8*)(Wm + (br0 + t * 16) * 512 + ka);
        }
#pragma unroll
        for (int tm = 0; tm < 4; ++tm)
#pragma unroll
            for (int tn = 0; tn < 4; ++tn)
                acc[tm][tn] = MFMA(a[tm], bfr[tn], acc[tm][tn]);
    }

#pragma unroll
    for (int tm = 0; tm < 4; ++tm) {
#pragma unroll
        for (int tn = 0; tn < 4; ++tn) {
            const int col = oc0 + wn * 64 + tn * 16 + l16;   // [0,512)
            const int hh  = col >> 6;
            const int d   = col & 63;
            const float bval = bb[col];
#pragma unroll
            for (int r = 0; r < 4; ++r) {
                const int R = m0 + wm * 64 + tm * 16 + quad * 4 + r; // global row
                const int bi = R >> 11;       // batch
                const int s  = R & 2047;      // seq pos
                const size_t hb = (size_t)(bi * NHEADS + hh) * (SEQ * HEADDIM);
                float val = acc[tm][tn][r] + bval;
                if (sec < 2) {
                    // rope: pairs are adjacent cols -> adjacent lanes
                    float other = __shfl_xor(val, 1);
                    const int p = d >> 1;
                    const float c  = cos_t[s * 32 + p];
                    const float sn = sin_t[s * 32 + p];
                    float res = ((d & 1) == 0) ? (val * c - other * sn)
                                               : (other * sn + val * c);
                    if (sec == 0) {
                        qws[hb + s * HEADDIM + d] = f2bf(res);
                    } else {
                        const int kt = s >> 6, sr = s & 63;
                        kws[hb + ((kt * 64 + sr) << 6)
                               + ((((d >> 3) ^ (sr & 7)) << 3) + (d & 7))] = f2bf(res);
                    }
                } else {
                    const int kt = s >> 6, sc = s & 63;
                    vtws[hb + ((kt * 64 + d) << 6)
                            + ((((sc >> 3) ^ (d & 7)) << 3) + (sc & 7))] = f2bf(val);
                }
            }
        }
    }
}

// ---------------- kernel 2: flash attention, LDS-staged, double-buffered ----------------
// grid: (SEQ/QTILE, B*H) = (16, 32). block 512 = 8 waves; each wave owns 16 q rows.
__global__ __launch_bounds__(512) void attn_kernel(
    const u16* __restrict__ qws, const u16* __restrict__ ktl,
    const u16* __restrict__ vtl,
    const int* __restrict__ vids, const float* __restrict__ mask,
    const float* __restrict__ u_same, const float* __restrict__ u_cross,
    u16* __restrict__ attn)
{
    __shared__ alignas(16) u16 kbuf[2][KTILE * 64];   // 8 KB each, swizzled tiles
    __shared__ alignas(16) u16 vbuf[2][KTILE * 64];
    __shared__ alignas(16) u16 pls[8][16][72];        // per-wave P tile, padded (144B stride)
    __shared__ int   bid[2][KTILE];
    __shared__ float bmk[2][KTILE];

    const int bh = blockIdx.y;
    const int b  = bh >> 3;
    const int h  = bh & 7;
    const int q0 = blockIdx.x * QTILE;

    const int tid  = threadIdx.x;
    const int w    = tid >> 6;                // 0..7
    const int lane = tid & 63;
    const int quad = lane >> 4;
    const int l16  = lane & 15;

    const float us = u_same[h];
    const float uc = u_cross[h];
    const size_t tb = (size_t)bh * (SEQ * HEADDIM);

    // Q A-fragments (fixed for the whole block): wave owns rows q0+w*16..+15
    const int qr = q0 + w * 16 + l16;
    const bf16x8 aq0 = *(const bf16x8*)(qws + tb + qr * HEADDIM + quad * 8);
    const bf16x8 aq1 = *(const bf16x8*)(qws + tb + qr * HEADDIM + 32 + quad * 8);

    int vq[4];
#pragma unroll
    for (int r = 0; r < 4; ++r)
        vq[r] = vids[b * SEQ + q0 + w * 16 + quad * 4 + r];

    float mi[4], li[4];
    f32x4 o[4] = {};
#pragma unroll
    for (int r = 0; r < 4; ++r) { mi[r] = -1e30f; li[r] = 0.0f; }

    auto stage = [&](int kt, int nb) {
        const u16* kg = ktl + tb + (size_t)kt * (KTILE * 64);
        const u16* vg = vtl + tb + (size_t)kt * (KTILE * 64);
        const int off = w * 512;             // wave covers 1 KB of each 8 KB tile
        gll16(kg + off + lane * 8, &kbuf[nb][off]);
        gll16(vg + off + lane * 8, &vbuf[nb][off]);
        if (w == 0) {
            gll4(vids + b * SEQ + kt * KTILE + lane, &bid[nb][0]);
            gll4(mask + b * SEQ + kt * KTILE + lane, &bmk[nb][0]);
        }
    };

    stage(0, 0);

    for (int kt = 0; kt < NKT; ++kt) {
        const int cur = kt & 1;
        __syncthreads();                    // drains vmcnt: tile cur ready; prev compute done
        if (kt + 1 < NKT) stage(kt + 1, cur ^ 1);

        float sv[4][4];

        // ---- scores: QK^T * scale + bias + mask ----
#pragma unroll
        for (int nt = 0; nt < 4; ++nt) {
            const int krow = nt * 16 + l16;
            const int r7   = krow & 7;
            const bf16x8 kb0 = *(const bf16x8*)&kbuf[cur][krow * 64 + ((quad ^ r7) << 3)];
            const bf16x8 kb1 = *(const bf16x8*)&kbuf[cur][krow * 64 + ((quad ^ r7 ^ 4) << 3)];
            f32x4 sc = {};
            sc = MFMA(aq0, kb0, sc);
            sc = MFMA(aq1, kb1, sc);
            const int   kv = bid[cur][krow];
            const float md = (1.0f - bmk[cur][krow]) * -1e9f;
#pragma unroll
            for (int r = 0; r < 4; ++r)
                sv[nt][r] = sc[r] * 0.125f + ((kv == vq[r]) ? us : uc) + md;
        }

        // ---- online softmax (rows live inside a 16-lane quad) ----
#pragma unroll
        for (int r = 0; r < 4; ++r) {
            float rm = fmaxf(fmaxf(sv[0][r], sv[1][r]), fmaxf(sv[2][r], sv[3][r]));
            rm = qmax16(rm);
            const float nm    = fmaxf(mi[r], rm);
            const float alpha = __expf(mi[r] - nm);
            float rs = 0.0f;
#pragma unroll
            for (int nt = 0; nt < 4; ++nt) {
                const float p = __expf(sv[nt][r] - nm);
                sv[nt][r] = p;
                rs += p;
            }
            rs = qsum16(rs);
            li[r] = li[r] * alpha + rs;
            mi[r] = nm;
#pragma unroll
            for (int nt = 0; nt < 4; ++nt) o[nt][r] *= alpha;
        }

        // ---- P: C-layout -> per-wave LDS -> A-layout (no barrier needed) ----
#pragma unroll
        for (int nt = 0; nt < 4; ++nt)
#pragma unroll
            for (int r = 0; r < 4; ++r)
                pls[w][quad * 4 + r][nt * 16 + l16] = f2bf(sv[nt][r]);

        const bf16x8 ap0 = *(const bf16x8*)&pls[w][l16][quad * 8];
        const bf16x8 ap1 = *(const bf16x8*)&pls[w][l16][32 + quad * 8];

        // ---- O += P @ V ----
#pragma unroll
        for (int nt = 0; nt < 4; ++nt) {
            const int vrow = nt * 16 + l16;
            const int r7   = vrow & 7;
            const bf16x8 vb0 = *(const bf16x8*)&vbuf[cur][vrow * 64 + ((quad ^ r7) << 3)];
            const bf16x8 vb1 = *(const bf16x8*)&vbuf[cur][vrow * 64 + ((quad ^ r7 ^ 4) << 3)];
            o[nt] = MFMA(ap0, vb0, o[nt]);
            o[nt] = MFMA(ap1, vb1, o[nt]);
        }
    }

    // ---- epilogue: normalize, write (B,S,H*64) bf16 ----
#pragma unroll
    for (int r = 0; r < 4; ++r) {
        const float inv = 1.0f / li[r];
        const int R = q0 + w * 16 + quad * 4 + r;
        const int rb = (b * SEQ + R) * DMODEL + h * HEADDIM;
#pragma unroll
        for (int nt = 0; nt < 4; ++nt)
            attn[rb + nt * 16 + l16] = f2bf(o[nt][r] * inv);
    }
}

// ---------------- kernel 3: output projection (128x128 tiles, fp32 out) ----------------
__global__ __launch_bounds__(256) void proj_kernel(
    const u16* __restrict__ a, const u16* __restrict__ Wo,
    const float* __restrict__ bo, float* __restrict__ out)
{
    const int m0 = blockIdx.x * 128;
    const int n0 = blockIdx.y * 128;         // [0,512)
    const int tid  = threadIdx.x;
    const int w    = tid >> 6;
    const int lane = tid & 63;
    const int quad = lane >> 4;
    const int l16  = lane & 15;
    const int wm = w & 1, wn = w >> 1;

    f32x4 acc[4][4] = {};
    const int ar0 = m0 + wm * 64 + l16;
    const int br0 = n0 + wn * 64 + l16;

#pragma unroll 2
    for (int k = 0; k < 512; k += 32) {
        const int ka = k + quad * 8;
        bf16x8 av[4], bv[4];
#pragma unroll
        for (int t = 0; t < 4; ++t) {
            av[t] = *(const bf16x8*)(a  + (ar0 + t * 16) * 512 + ka);
            bv[t] = *(const bf16x8*)(Wo + (br0 + t * 16) * 512 + ka);
        }
#pragma unroll
        for (int tm = 0; tm < 4; ++tm)
#pragma unroll
            for (int tn = 0; tn < 4; ++tn)
                acc[tm][tn] = MFMA(av[tm], bv[tn], acc[tm][tn]);
    }

#pragma unroll
    for (int tm = 0; tm < 4; ++tm) {
#pragma unroll
        for (int tn = 0; tn < 4; ++tn) {
            const int col = n0 + wn * 64 + tn * 16 + l16;
            const float bval = bo[col];
#pragma unroll
            for (int r = 0; r < 4; ++r) {
                const int R = m0 + wm * 64 + tm * 16 + quad * 4 + r;
                out[R * 512 + col] = acc[tm][tn][r] + bval;
            }
        }
    }
}

// ---------------- launch ----------------
extern "C" void kernel_launch(void* const* d_in, const int* in_sizes, int n_in,
                              void* d_out, int out_size, void* d_ws, size_t ws_size,
                              hipStream_t stream) {
    const float* x    = (const float*)d_in[0];
    const int*   vids = (const int*)d_in[1];
    const float* mask = (const float*)d_in[2];
    const float* Wq = (const float*)d_in[3];
    const float* bq = (const float*)d_in[4];
    const float* Wk = (const float*)d_in[5];
    const float* bk = (const float*)d_in[6];
    const float* Wv = (const float*)d_in[7];
    const float* bv = (const float*)d_in[8];
    const float* Wo = (const float*)d_in[9];
    const float* bo = (const float*)d_in[10];
    const float* usame  = (const float*)d_in[11];
    const float* ucross = (const float*)d_in[12];
    float* out = (float*)d_out;

    // workspace layout (34.5 MB total)
    u16* xbf  = (u16*)d_ws;                 // 8 MB; reused as attention output
    u16* wqbf = xbf + NX;                   // 512 KB each
    u16* wkbf = wqbf + NW;
    u16* wvbf = wkbf + NW;
    u16* wobf = wvbf + NW;
    float* cos_t = (float*)(wobf + NW);     // 256 KB
    float* sin_t = cos_t + SEQ * 32;        // 256 KB
    u16* qws  = (u16*)(sin_t + SEQ * 32);   // 8 MB each
    u16* kws  = qws + (size_t)BATCH * NHEADS * SEQ * HEADDIM;
    u16* vtws = kws + (size_t)BATCH * NHEADS * SEQ * HEADDIM;
    u16* attn = xbf;   // reuse: qkv_kernel has finished with xbf before attn writes

    cvt_rope_kernel<<<(NCVT4 + SEQ * 32 / 4 + 255) / 256, 256, 0, stream>>>(
        x, Wq, Wk, Wv, Wo, xbf, wqbf, wkbf, wvbf, wobf, cos_t, sin_t);

    dim3 g1(MTOT / 128, 3 * DMODEL / 128);  // 64 x 12
    qkv_kernel<<<g1, 256, 0, stream>>>(xbf, wqbf, bq, wkbf, bk, wvbf, bv,
                                       cos_t, sin_t, qws, kws, vtws);

    dim3 g2(SEQ / QTILE, BATCH * NHEADS);   // 16 x 32
    attn_kernel<<<g2, 512, 0, stream>>>(qws, kws, vtws, vids, mask,
                                        usame, ucross, attn);

    dim3 g3(MTOT / 128, DMODEL / 128);      // 64 x 4
    proj_kernel<<<g3, 256, 0, stream>>>(attn, wobf, bo, out);
}

// Round 5
// 221.220 us; speedup vs baseline: 2.0679x; 1.2947x over previous
//
#include <hip/hip_runtime.h>

// ---------------- problem constants ----------------
#define BATCH   4
#define SEQ     2048
#define DMODEL  512
#define NHEADS  8
#define HEADDIM 64
#define MTOT    (BATCH*SEQ)      // 8192 rows
#define NX      (MTOT*DMODEL)    // 4194304 x elements
#define NW      (DMODEL*DMODEL)  // 262144 weight elements
#define QTILE   128
#define KTILE   64
#define NKT     (SEQ/KTILE)      // 32

#define LOG2E   1.4426950408889634f
#define SCL2    0.18033688011112042f      // 0.125 * log2e
#define SHIFT   14.426950408889634f       // 10 * log2e (overflow headroom shift)
// ---------------------------------------------------

typedef unsigned short u16;
typedef __bf16 bf16x8 __attribute__((ext_vector_type(8)));
typedef float  f32x4  __attribute__((ext_vector_type(4)));
typedef unsigned short u16x4 __attribute__((ext_vector_type(4)));

#define MFMA(a,b,c) __builtin_amdgcn_mfma_f32_16x16x32_bf16(a,b,c,0,0,0)

__device__ __forceinline__ u16 f2bf(float f) {
    unsigned u = __float_as_uint(f);
    u += 0x7FFFu + ((u >> 16) & 1u);   // round-to-nearest-even
    return (u16)(u >> 16);
}

__device__ __forceinline__ float qsum16(float v) {
    v += __shfl_xor(v, 1);
    v += __shfl_xor(v, 2);
    v += __shfl_xor(v, 4);
    v += __shfl_xor(v, 8);
    return v;
}

// async global->LDS (wave-uniform LDS base + lane*size)
__device__ __forceinline__ void gll16(const void* g, void* l) {
    __builtin_amdgcn_global_load_lds((const __attribute__((address_space(1))) void*)g,
                                     (__attribute__((address_space(3))) void*)l, 16, 0, 0);
}
__device__ __forceinline__ void gll4(const void* g, void* l) {
    __builtin_amdgcn_global_load_lds((const __attribute__((address_space(1))) void*)g,
                                     (__attribute__((address_space(3))) void*)l, 4, 0, 0);
}

// ---------------- kernel 0: fp32 -> bf16 converts + rope tables ----------------
#define NCVT4 ((NX + 4*NW)/4)    // 1310720 float4 groups
__global__ __launch_bounds__(256) void cvt_rope_kernel(
    const float* __restrict__ x,
    const float* __restrict__ wq, const float* __restrict__ wk,
    const float* __restrict__ wv, const float* __restrict__ wo,
    u16* __restrict__ xbf,
    u16* __restrict__ wqbf, u16* __restrict__ wkbf,
    u16* __restrict__ wvbf, u16* __restrict__ wobf,
    float* __restrict__ cos_t, float* __restrict__ sin_t)
{
    int i4 = blockIdx.x * 256 + threadIdx.x;
    if (i4 < NCVT4) {
        int i = i4 * 4;
        const float* s; u16* d; int o;
        if (i < NX) { s = x; d = xbf; o = i; }
        else {
            int j = i - NX;
            int r = j >> 18;            // NW = 2^18
            o = j & (NW - 1);
            s = (r == 0) ? wq : (r == 1) ? wk : (r == 2) ? wv : wo;
            d = (r == 0) ? wqbf : (r == 1) ? wkbf : (r == 2) ? wvbf : wobf;
        }
        float4 v = *(const float4*)(s + o);
        u16x4 u = { f2bf(v.x), f2bf(v.y), f2bf(v.z), f2bf(v.w) };
        *(u16x4*)(d + o) = u;
    } else {
        int r = i4 - NCVT4;             // [0, 16384)
        if (r < SEQ * 32 / 4) {
            int idx = r * 4;
            int s  = idx >> 5;
            int p0 = idx & 31;
#pragma unroll
            for (int t = 0; t < 4; ++t) {
                int p = p0 + t;
                float inv = __expf(-0.5756462732485115f * (float)(p & 15));
                float ang = (float)s * inv;
                cos_t[idx + t] = cosf(ang);
                sin_t[idx + t] = sinf(ang);
            }
        }
    }
}

// ---------------- kernel 1: fused QKV projection + RoPE (128x128, LDS-staged) ----------------
// Q: rope, linear (bh, s, d).
// K: rope, tiled-swizzled: tile (bh,kt) 64x64, elem (sr,d) at
//    tile*4096 + sr*64 + ((d>>3 ^ (sr&7))<<3) + (d&7)
// V: transposed tiled-swizzled: elem (d, sc) at
//    tile*4096 + d*64 + ((sc>>3 ^ (d&7))<<3) + (sc&7)
__global__ __launch_bounds__(256) void qkv_kernel(
    const u16* __restrict__ x,
    const u16* __restrict__ Wq, const float* __restrict__ bq,
    const u16* __restrict__ Wk, const float* __restrict__ bk,
    const u16* __restrict__ Wv, const float* __restrict__ bv,
    const float* __restrict__ cos_t, const float* __restrict__ sin_t,
    u16* __restrict__ qws, u16* __restrict__ kws, u16* __restrict__ vtws)
{
    __shared__ alignas(16) u16 As[128 * 64];   // 16 KB, XOR-swizzled k-blocks
    __shared__ alignas(16) u16 Bs[128 * 64];

    const int m0 = blockIdx.x * 128;         // row tile (64 tiles)
    const int n0 = blockIdx.y * 128;         // col tile over 1536 (12 tiles)
    const int tid  = threadIdx.x;
    const int w    = tid >> 6;
    const int lane = tid & 63;
    const int quad = lane >> 4;
    const int l16  = lane & 15;
    const int wm = w & 1, wn = w >> 1;       // 2x2 wave grid, each wave 64x64

    const int sec = n0 >> 9;                 // 0=Q 1=K 2=V
    const int oc0 = n0 & 511;
    const u16*   Wm = (sec == 0) ? Wq : (sec == 1 ? Wk : Wv);
    const float* bb = (sec == 0) ? bq : (sec == 1 ? bk : bv);

    f32x4 acc[4][4] = {};

    for (int kb = 0; kb < 8; ++kb) {
        // ---- stage A,B tiles: slot s covers LDS bytes [s*16, s*16+16) ----
#pragma unroll
        for (int it = 0; it < 4; ++it) {
            const int s   = it * 256 + tid;
            const int row = s >> 3;
            const int cb  = s & 7;
            const int gcol = kb * 64 + (((cb ^ (row & 7))) << 3);
            gll16(x  + (m0  + row) * 512 + gcol, &As[s * 8]);
            gll16(Wm + (oc0 + row) * 512 + gcol, &Bs[s * 8]);
        }
        __syncthreads();

#pragma unroll
        for (int ks = 0; ks < 2; ++ks) {
            bf16x8 a[4], bfr[4];
#pragma unroll
            for (int t = 0; t < 4; ++t) {
                const int arow = wm * 64 + t * 16 + l16;
                a[t]   = *(const bf16x8*)&As[arow * 64 + (((ks * 4 + quad) ^ (arow & 7)) << 3)];
                const int brow = wn * 64 + t * 16 + l16;
                bfr[t] = *(const bf16x8*)&Bs[brow * 64 + (((ks * 4 + quad) ^ (brow & 7)) << 3)];
            }
#pragma unroll
            for (int tm = 0; tm < 4; ++tm)
#pragma unroll
                for (int tn = 0; tn < 4; ++tn)
                    acc[tm][tn] = MFMA(a[tm], bfr[tn], acc[tm][tn]);
        }
        __syncthreads();
    }

#pragma unroll
    for (int tm = 0; tm < 4; ++tm) {
#pragma unroll
        for (int tn = 0; tn < 4; ++tn) {
            const int col = oc0 + wn * 64 + tn * 16 + l16;   // [0,512)
            const int hh  = col >> 6;
            const int d   = col & 63;
            const float bval = bb[col];
#pragma unroll
            for (int r = 0; r < 4; ++r) {
                const int R = m0 + wm * 64 + tm * 16 + quad * 4 + r; // global row
                const int bi = R >> 11;       // batch
                const int s  = R & 2047;      // seq pos
                const size_t hb = (size_t)(bi * NHEADS + hh) * (SEQ * HEADDIM);
                float val = acc[tm][tn][r] + bval;
                if (sec < 2) {
                    // rope: pairs are adjacent cols -> adjacent lanes
                    float other = __shfl_xor(val, 1);
                    const int p = d >> 1;
                    const float c  = cos_t[s * 32 + p];
                    const float sn = sin_t[s * 32 + p];
                    float res = ((d & 1) == 0) ? (val * c - other * sn)
                                               : (other * sn + val * c);
                    if (sec == 0) {
                        qws[hb + s * HEADDIM + d] = f2bf(res);
                    } else {
                        const int kt = s >> 6, sr = s & 63;
                        kws[hb + ((kt * 64 + sr) << 6)
                               + ((((d >> 3) ^ (sr & 7)) << 3) + (d & 7))] = f2bf(res);
                    }
                } else {
                    const int kt = s >> 6, sc = s & 63;
                    vtws[hb + ((kt * 64 + d) << 6)
                            + ((((sc >> 3) ^ (d & 7)) << 3) + (sc & 7))] = f2bf(val);
                }
            }
        }
    }
}

// ---------------- kernel 2: flash attention, no-rescale softmax ----------------
// grid: (SEQ/QTILE, B*H) = (16, 32). block 512 = 8 waves; each wave owns 16 q rows.
// exp(s - 10) computed directly in exp2 domain; li summed lane-locally, reduced once.
__global__ __launch_bounds__(512) void attn_kernel(
    const u16* __restrict__ qws, const u16* __restrict__ ktl,
    const u16* __restrict__ vtl,
    const int* __restrict__ vids, const float* __restrict__ mask,
    const float* __restrict__ u_same, const float* __restrict__ u_cross,
    u16* __restrict__ attn)
{
    __shared__ alignas(16) u16 kbuf[2][KTILE * 64];   // 8 KB each, swizzled tiles
    __shared__ alignas(16) u16 vbuf[2][KTILE * 64];
    __shared__ alignas(16) u16 pls[8][16][72];        // per-wave P tile, padded (144B stride)
    __shared__ int   bid[2][KTILE];
    __shared__ float bmk[2][KTILE];

    const int bh = blockIdx.y;
    const int b  = bh >> 3;
    const int h  = bh & 7;
    const int q0 = blockIdx.x * QTILE;

    const int tid  = threadIdx.x;
    const int w    = tid >> 6;                // 0..7
    const int lane = tid & 63;
    const int quad = lane >> 4;
    const int l16  = lane & 15;

    const float us2 = u_same[h]  * LOG2E;
    const float uc2 = u_cross[h] * LOG2E;
    const size_t tb = (size_t)bh * (SEQ * HEADDIM);

    // Q A-fragments (fixed for the whole block): wave owns rows q0+w*16..+15
    const int qr = q0 + w * 16 + l16;
    const bf16x8 aq0 = *(const bf16x8*)(qws + tb + qr * HEADDIM + quad * 8);
    const bf16x8 aq1 = *(const bf16x8*)(qws + tb + qr * HEADDIM + 32 + quad * 8);

    int vq[4];
#pragma unroll
    for (int r = 0; r < 4; ++r)
        vq[r] = vids[b * SEQ + q0 + w * 16 + quad * 4 + r];

    float li[4] = {0.f, 0.f, 0.f, 0.f};
    f32x4 o[4] = {};

    auto stage = [&](int kt, int nb) {
        const u16* kg = ktl + tb + (size_t)kt * (KTILE * 64);
        const u16* vg = vtl + tb + (size_t)kt * (KTILE * 64);
        const int off = w * 512;             // wave covers 1 KB of each 8 KB tile
        gll16(kg + off + lane * 8, &kbuf[nb][off]);
        gll16(vg + off + lane * 8, &vbuf[nb][off]);
        if (w == 0) {
            gll4(vids + b * SEQ + kt * KTILE + lane, &bid[nb][0]);
            gll4(mask + b * SEQ + kt * KTILE + lane, &bmk[nb][0]);
        }
    };

    stage(0, 0);

    for (int kt = 0; kt < NKT; ++kt) {
        const int cur = kt & 1;
        __syncthreads();                    // drains vmcnt: tile cur ready; prev compute done
        if (kt + 1 < NKT) stage(kt + 1, cur ^ 1);

        // ---- scores -> p = exp2(sc*0.125*log2e + bias2 + mask2 - SHIFT), pack to LDS ----
#pragma unroll
        for (int nt = 0; nt < 4; ++nt) {
            const int krow = nt * 16 + l16;
            const int r7   = krow & 7;
            const bf16x8 kb0 = *(const bf16x8*)&kbuf[cur][krow * 64 + ((quad ^ r7) << 3)];
            const bf16x8 kb1 = *(const bf16x8*)&kbuf[cur][krow * 64 + ((quad ^ r7 ^ 4) << 3)];
            f32x4 sc = {};
            sc = MFMA(aq0, kb0, sc);
            sc = MFMA(aq1, kb1, sc);
            const int   kv  = bid[cur][krow];
            const float mdl = fmaf(1.0f - bmk[cur][krow], -1.4426950408889634e9f, -SHIFT);
#pragma unroll
            for (int r = 0; r < 4; ++r) {
                const float sel = (kv == vq[r]) ? us2 : uc2;
                const float p = exp2f(fmaf(sc[r], SCL2, sel + mdl));
                li[r] += p;
                pls[w][quad * 4 + r][nt * 16 + l16] = f2bf(p);
            }
        }

        const bf16x8 ap0 = *(const bf16x8*)&pls[w][l16][quad * 8];
        const bf16x8 ap1 = *(const bf16x8*)&pls[w][l16][32 + quad * 8];

        // ---- O += P @ V (no rescale) ----
#pragma unroll
        for (int nt = 0; nt < 4; ++nt) {
            const int vrow = nt * 16 + l16;
            const int r7   = vrow & 7;
            const bf16x8 vb0 = *(const bf16x8*)&vbuf[cur][vrow * 64 + ((quad ^ r7) << 3)];
            const bf16x8 vb1 = *(const bf16x8*)&vbuf[cur][vrow * 64 + ((quad ^ r7 ^ 4) << 3)];
            o[nt] = MFMA(ap0, vb0, o[nt]);
            o[nt] = MFMA(ap1, vb1, o[nt]);
        }
    }

    // ---- epilogue: reduce li across the quad-row group, normalize, write ----
#pragma unroll
    for (int r = 0; r < 4; ++r) {
        const float inv = 1.0f / qsum16(li[r]);
        const int R = q0 + w * 16 + quad * 4 + r;
        const int rb = (b * SEQ + R) * DMODEL + h * HEADDIM;
#pragma unroll
        for (int nt = 0; nt < 4; ++nt)
            attn[rb + nt * 16 + l16] = f2bf(o[nt][r] * inv);
    }
}

// ---------------- kernel 3: output projection (128x128, LDS-staged, fp32 out) ----------------
__global__ __launch_bounds__(256) void proj_kernel(
    const u16* __restrict__ a, const u16* __restrict__ Wo,
    const float* __restrict__ bo, float* __restrict__ out)
{
    __shared__ alignas(16) u16 As[128 * 64];
    __shared__ alignas(16) u16 Bs[128 * 64];

    const int m0 = blockIdx.x * 128;
    const int n0 = blockIdx.y * 128;         // [0,512)
    const int tid  = threadIdx.x;
    const int w    = tid >> 6;
    const int lane = tid & 63;
    const int quad = lane >> 4;
    const int l16  = lane & 15;
    const int wm = w & 1, wn = w >> 1;

    f32x4 acc[4][4] = {};

    for (int kb = 0; kb < 8; ++kb) {
#pragma unroll
        for (int it = 0; it < 4; ++it) {
            const int s   = it * 256 + tid;
            const int row = s >> 3;
            const int cb  = s & 7;
            const int gcol = kb * 64 + (((cb ^ (row & 7))) << 3);
            gll16(a  + (m0 + row) * 512 + gcol, &As[s * 8]);
            gll16(Wo + (n0 + row) * 512 + gcol, &Bs[s * 8]);
        }
        __syncthreads();

#pragma unroll
        for (int ks = 0; ks < 2; ++ks) {
            bf16x8 av[4], bv[4];
#pragma unroll
            for (int t = 0; t < 4; ++t) {
                const int arow = wm * 64 + t * 16 + l16;
                av[t] = *(const bf16x8*)&As[arow * 64 + (((ks * 4 + quad) ^ (arow & 7)) << 3)];
                const int brow = wn * 64 + t * 16 + l16;
                bv[t] = *(const bf16x8*)&Bs[brow * 64 + (((ks * 4 + quad) ^ (brow & 7)) << 3)];
            }
#pragma unroll
            for (int tm = 0; tm < 4; ++tm)
#pragma unroll
                for (int tn = 0; tn < 4; ++tn)
                    acc[tm][tn] = MFMA(av[tm], bv[tn], acc[tm][tn]);
        }
        __syncthreads();
    }

#pragma unroll
    for (int tm = 0; tm < 4; ++tm) {
#pragma unroll
        for (int tn = 0; tn < 4; ++tn) {
            const int col = n0 + wn * 64 + tn * 16 + l16;
            const float bval = bo[col];
#pragma unroll
            for (int r = 0; r < 4; ++r) {
                const int R = m0 + wm * 64 + tm * 16 + quad * 4 + r;
                out[R * 512 + col] = acc[tm][tn][r] + bval;
            }
        }
    }
}

// ---------------- launch ----------------
extern "C" void kernel_launch(void* const* d_in, const int* in_sizes, int n_in,
                              void* d_out, int out_size, void* d_ws, size_t ws_size,
                              hipStream_t stream) {
    const float* x    = (const float*)d_in[0];
    const int*   vids = (const int*)d_in[1];
    const float* mask = (const float*)d_in[2];
    const float* Wq = (const float*)d_in[3];
    const float* bq = (const float*)d_in[4];
    const float* Wk = (const float*)d_in[5];
    const float* bk = (const float*)d_in[6];
    const float* Wv = (const float*)d_in[7];
    const float* bv = (const float*)d_in[8];
    const float* Wo = (const float*)d_in[9];
    const float* bo = (const float*)d_in[10];
    const float* usame  = (const float*)d_in[11];
    const float* ucross = (const float*)d_in[12];
    float* out = (float*)d_out;

    // workspace layout (34.5 MB total)
    u16* xbf  = (u16*)d_ws;                 // 8 MB; reused as attention output
    u16* wqbf = xbf + NX;                   // 512 KB each
    u16* wkbf = wqbf + NW;
    u16* wvbf = wkbf + NW;
    u16* wobf = wvbf + NW;
    float* cos_t = (float*)(wobf + NW);     // 256 KB
    float* sin_t = cos_t + SEQ * 32;        // 256 KB
    u16* qws  = (u16*)(sin_t + SEQ * 32);   // 8 MB each
    u16* kws  = qws + (size_t)BATCH * NHEADS * SEQ * HEADDIM;
    u16* vtws = kws + (size_t)BATCH * NHEADS * SEQ * HEADDIM;
    u16* attn = xbf;   // reuse: qkv_kernel has finished with xbf before attn writes

    cvt_rope_kernel<<<(NCVT4 + SEQ * 32 / 4 + 255) / 256, 256, 0, stream>>>(
        x, Wq, Wk, Wv, Wo, xbf, wqbf, wkbf, wvbf, wobf, cos_t, sin_t);

    dim3 g1(MTOT / 128, 3 * DMODEL / 128);  // 64 x 12
    qkv_kernel<<<g1, 256, 0, stream>>>(xbf, wqbf, bq, wkbf, bk, wvbf, bv,
                                       cos_t, sin_t, qws, kws, vtws);

    dim3 g2(SEQ / QTILE, BATCH * NHEADS);   // 16 x 32
    attn_kernel<<<g2, 512, 0, stream>>>(qws, kws, vtws, vids, mask,
                                        usame, ucross, attn);

    dim3 g3(MTOT / 128, DMODEL / 128);      // 64 x 4
    proj_kernel<<<g3, 256, 0, stream>>>(attn, wobf, bo, out);
}

// Round 6
// 207.087 us; speedup vs baseline: 2.2090x; 1.0682x over previous
//
#include <hip/hip_runtime.h>
#include <hip/hip_bf16.h>

// ---------------- problem constants ----------------
#define BATCH   4
#define SEQ     2048
#define DMODEL  512
#define NHEADS  8
#define HEADDIM 64
#define MTOT    (BATCH*SEQ)      // 8192 rows
#define NX      (MTOT*DMODEL)    // 4194304 x elements
#define NW      (DMODEL*DMODEL)  // 262144 weight elements
#define QTILE   128
#define KTILE   64
#define NKT     (SEQ/KTILE)      // 32

#define LOG2E   1.4426950408889634f
#define SCL2    0.18033688011112042f      // 0.125 * log2e
#define SHIFT   14.426950408889634f       // 10 * log2e (overflow headroom shift)
// ---------------------------------------------------

typedef unsigned short u16;
typedef __bf16 bf16x8 __attribute__((ext_vector_type(8)));
typedef float  f32x4  __attribute__((ext_vector_type(4)));
typedef unsigned short u16x4 __attribute__((ext_vector_type(4)));
typedef unsigned u32x2 __attribute__((ext_vector_type(2)));

#define MFMA(a,b,c) __builtin_amdgcn_mfma_f32_16x16x32_bf16(a,b,c,0,0,0)

__device__ __forceinline__ u16 f2bf(float f) {
    unsigned u = __float_as_uint(f);
    u += 0x7FFFu + ((u >> 16) & 1u);   // round-to-nearest-even
    return (u16)(u >> 16);
}

// two f32 -> packed bf16 pair (low = a), RNE; lowers to v_cvt_pk_bf16_f32 on gfx950
__device__ __forceinline__ unsigned pk_bf16(float a, float b) {
    union { __hip_bfloat162 h; unsigned u; } cv;
    cv.h = __float22bfloat162_rn(make_float2(a, b));
    return cv.u;
}

__device__ __forceinline__ float qsum16(float v) {
    v += __shfl_xor(v, 1);
    v += __shfl_xor(v, 2);
    v += __shfl_xor(v, 4);
    v += __shfl_xor(v, 8);
    return v;
}

// async global->LDS (wave-uniform LDS base + lane*size)
__device__ __forceinline__ void gll16(const void* g, void* l) {
    __builtin_amdgcn_global_load_lds((const __attribute__((address_space(1))) void*)g,
                                     (__attribute__((address_space(3))) void*)l, 16, 0, 0);
}
__device__ __forceinline__ void gll4(const void* g, void* l) {
    __builtin_amdgcn_global_load_lds((const __attribute__((address_space(1))) void*)g,
                                     (__attribute__((address_space(3))) void*)l, 4, 0, 0);
}

// ---------------- kernel 0: fp32 -> bf16 converts + rope cos/sin table ----------------
#define NCVT4 ((NX + 4*NW)/4)    // 1310720 float4 groups
__global__ __launch_bounds__(256) void cvt_rope_kernel(
    const float* __restrict__ x,
    const float* __restrict__ wq, const float* __restrict__ wk,
    const float* __restrict__ wv, const float* __restrict__ wo,
    u16* __restrict__ xbf,
    u16* __restrict__ wqbf, u16* __restrict__ wkbf,
    u16* __restrict__ wvbf, u16* __restrict__ wobf,
    float2* __restrict__ cst)
{
    int i4 = blockIdx.x * 256 + threadIdx.x;
    if (i4 < NCVT4) {
        int i = i4 * 4;
        const float* s; u16* d; int o;
        if (i < NX) { s = x; d = xbf; o = i; }
        else {
            int j = i - NX;
            int r = j >> 18;            // NW = 2^18
            o = j & (NW - 1);
            s = (r == 0) ? wq : (r == 1) ? wk : (r == 2) ? wv : wo;
            d = (r == 0) ? wqbf : (r == 1) ? wkbf : (r == 2) ? wvbf : wobf;
        }
        float4 v = *(const float4*)(s + o);
        u16x4 u = { f2bf(v.x), f2bf(v.y), f2bf(v.z), f2bf(v.w) };
        *(u16x4*)(d + o) = u;
    } else {
        int r = i4 - NCVT4;             // [0, 16384)
        if (r < SEQ * 32 / 4) {
            int idx = r * 4;
            int s  = idx >> 5;
            int p0 = idx & 31;
#pragma unroll
            for (int t = 0; t < 4; ++t) {
                int p = p0 + t;
                float inv = __expf(-0.5756462732485115f * (float)(p & 15));
                float ang = (float)s * inv;
                cst[idx + t] = make_float2(cosf(ang), sinf(ang));
            }
        }
    }
}

// ---------------- kernel 1: fused QKV projection + RoPE (128x128, LDS-staged) ----------------
// Q: rope, linear (bh, s, d).   K: rope, linear (bh, s, d).
// V: transposed linear (bh, d, s)  (attention applies the XOR swizzle at stage time)
__global__ __launch_bounds__(256) void qkv_kernel(
    const u16* __restrict__ x,
    const u16* __restrict__ Wq, const float* __restrict__ bq,
    const u16* __restrict__ Wk, const float* __restrict__ bk,
    const u16* __restrict__ Wv, const float* __restrict__ bv,
    const float2* __restrict__ cst,
    u16* __restrict__ qws, u16* __restrict__ kws, u16* __restrict__ vtws)
{
    __shared__ alignas(16) u16 As[128 * 64];   // 16 KB, XOR-swizzled k-blocks
    __shared__ alignas(16) u16 Bs[128 * 64];

    const int m0 = blockIdx.x * 128;         // row tile (64 tiles)
    const int n0 = blockIdx.y * 128;         // col tile over 1536 (12 tiles)
    const int tid  = threadIdx.x;
    const int w    = tid >> 6;
    const int lane = tid & 63;
    const int quad = lane >> 4;
    const int l16  = lane & 15;
    const int wm = w & 1, wn = w >> 1;       // 2x2 wave grid, each wave 64x64

    const int sec = n0 >> 9;                 // 0=Q 1=K 2=V
    const int oc0 = n0 & 511;
    const u16*   Wm = (sec == 0) ? Wq : (sec == 1 ? Wk : Wv);
    const float* bb = (sec == 0) ? bq : (sec == 1 ? bk : bv);
    const float  sgn = (l16 & 1) ? 1.0f : -1.0f;   // rope sign, lane-parity const

    f32x4 acc[4][4] = {};

    for (int kb = 0; kb < 8; ++kb) {
        // ---- stage A,B tiles: slot s covers LDS bytes [s*16, s*16+16) ----
#pragma unroll
        for (int it = 0; it < 4; ++it) {
            const int s   = it * 256 + tid;
            const int row = s >> 3;
            const int cb  = s & 7;
            const int gcol = kb * 64 + (((cb ^ (row & 7))) << 3);
            gll16(x  + (m0  + row) * 512 + gcol, &As[s * 8]);
            gll16(Wm + (oc0 + row) * 512 + gcol, &Bs[s * 8]);
        }
        __syncthreads();

#pragma unroll
        for (int ks = 0; ks < 2; ++ks) {
            bf16x8 a[4], bfr[4];
#pragma unroll
            for (int t = 0; t < 4; ++t) {
                const int arow = wm * 64 + t * 16 + l16;
                a[t]   = *(const bf16x8*)&As[arow * 64 + (((ks * 4 + quad) ^ (arow & 7)) << 3)];
                const int brow = wn * 64 + t * 16 + l16;
                bfr[t] = *(const bf16x8*)&Bs[brow * 64 + (((ks * 4 + quad) ^ (brow & 7)) << 3)];
            }
#pragma unroll
            for (int tm = 0; tm < 4; ++tm)
#pragma unroll
                for (int tn = 0; tn < 4; ++tn)
                    acc[tm][tn] = MFMA(a[tm], bfr[tn], acc[tm][tn]);
        }
        __syncthreads();
    }

#pragma unroll
    for (int tm = 0; tm < 4; ++tm) {
        const int R0 = m0 + wm * 64 + tm * 16 + quad * 4;   // rows R0..R0+3
        const int bi = R0 >> 11;
        const int s0 = R0 & 2047;
#pragma unroll
        for (int tn = 0; tn < 4; ++tn) {
            const int col = oc0 + wn * 64 + tn * 16 + l16;   // [0,512)
            const int hh  = col >> 6;
            const int d   = col & 63;
            const float bval = bb[col];
            const size_t hb = (size_t)(bi * NHEADS + hh) * (SEQ * HEADDIM);
            float res[4];
            if (sec < 2) {
#pragma unroll
                for (int r = 0; r < 4; ++r) {
                    float val = acc[tm][tn][r] + bval;
                    float other = __shfl_xor(val, 1);
                    float2 cs = cst[(s0 + r) * 32 + (d >> 1)];
                    res[r] = fmaf(val, cs.x, other * (sgn * cs.y));
                }
                const unsigned p01 = pk_bf16(res[0], res[1]);
                const unsigned p23 = pk_bf16(res[2], res[3]);
                u16* dp = ((sec == 0) ? qws : kws) + hb + (size_t)s0 * HEADDIM + d;
                dp[0]   = (u16)p01;  dp[64]  = (u16)(p01 >> 16);
                dp[128] = (u16)p23;  dp[192] = (u16)(p23 >> 16);
            } else {
#pragma unroll
                for (int r = 0; r < 4; ++r) res[r] = acc[tm][tn][r] + bval;
                u32x2 pv = { pk_bf16(res[0], res[1]), pk_bf16(res[2], res[3]) };
                *(u32x2*)(vtws + hb + (size_t)d * SEQ + s0) = pv;
            }
        }
    }
}

// ---------------- kernel 2: flash attention, no-rescale softmax, kt-unrolled x2 ----------------
// grid: (SEQ/QTILE, B*H) = (16, 32). block 512 = 8 waves; each wave owns 16 q rows.
__global__ __launch_bounds__(512, 4) void attn_kernel(
    const u16* __restrict__ qws, const u16* __restrict__ kws,
    const u16* __restrict__ vtl,
    const int* __restrict__ vids, const float* __restrict__ mask,
    const float* __restrict__ u_same, const float* __restrict__ u_cross,
    u16* __restrict__ attn)
{
    __shared__ alignas(16) u16 kbuf[2][KTILE * 64];   // 8 KB each, swizzled tiles
    __shared__ alignas(16) u16 vbuf[2][KTILE * 64];
    __shared__ alignas(16) u16 pls[8][16][72];        // per-wave P tile, padded (144B stride)
    __shared__ int   bid[2][KTILE];
    __shared__ float bmk[2][KTILE];

    const int bh = blockIdx.y;
    const int b  = bh >> 3;
    const int h  = bh & 7;
    const int q0 = blockIdx.x * QTILE;

    const int tid  = threadIdx.x;
    const int w    = tid >> 6;                // 0..7
    const int lane = tid & 63;
    const int quad = lane >> 4;
    const int l16  = lane & 15;

    const float us2 = u_same[h]  * LOG2E;
    const float uc2 = u_cross[h] * LOG2E;
    const size_t tb = (size_t)bh * (SEQ * HEADDIM);

    // Q A-fragments (fixed for the whole block): wave owns rows q0+w*16..+15
    const int qr = q0 + w * 16 + l16;
    const bf16x8 aq0 = *(const bf16x8*)(qws + tb + qr * HEADDIM + quad * 8);
    const bf16x8 aq1 = *(const bf16x8*)(qws + tb + qr * HEADDIM + 32 + quad * 8);

    int vq[4];
#pragma unroll
    for (int r = 0; r < 4; ++r)
        vq[r] = vids[b * SEQ + q0 + w * 16 + quad * 4 + r];

    float li[4] = {0.f, 0.f, 0.f, 0.f};
    f32x4 o[4] = {};

    // stage from LINEAR K (s,d) and V^T (d,s), applying XOR swizzle on the SOURCE address
    const int srow = w * 8 + (lane >> 3);     // tile row this lane stages
    const int scb  = lane & 7;                // 8-elem block within row
    const int soff = ((scb ^ (srow & 7)) << 3);
    auto stage = [&](int kt, int nb) {
        const int k0 = kt * KTILE;
        gll16(kws + tb + (size_t)(k0 + srow) * HEADDIM + soff, &kbuf[nb][w * 512 + (lane & 7) * 8 + ((lane >> 3) & 7) * 0 + lane * 8 - lane * 8 + (srow - w * 8) * 64 + scb * 8]);
        gll16(vtl + tb + (size_t)srow * SEQ + k0 + soff,        &vbuf[nb][(srow - w * 8) * 64 + w * 512 + scb * 8]);
        if (w == 0) {
            gll4(vids + b * SEQ + k0 + lane, &bid[nb][0]);
            gll4(mask + b * SEQ + k0 + lane, &bmk[nb][0]);
        }
    };

    auto body = [&](const int cur) {   // cur is a literal at each call site -> const LDS addrs
        // ---- scores -> p = exp2(sc*SCL2 + sel + mdl), pack to per-wave LDS ----
#pragma unroll
        for (int nt = 0; nt < 4; ++nt) {
            const int krow = nt * 16 + l16;
            const int r7   = krow & 7;
            const bf16x8 kb0 = *(const bf16x8*)&kbuf[cur][krow * 64 + ((quad ^ r7) << 3)];
            const bf16x8 kb1 = *(const bf16x8*)&kbuf[cur][krow * 64 + ((quad ^ r7 ^ 4) << 3)];
            f32x4 sc = {};
            sc = MFMA(aq0, kb0, sc);
            sc = MFMA(aq1, kb1, sc);
            const int   kv  = bid[cur][krow];
            const float mdl = fmaf(bmk[cur][krow], 1.4426950408889634e9f,
                                   -1.4426950408889634e9f - SHIFT);
            const float as_ = us2 + mdl;
            const float ac_ = uc2 + mdl;
            float p[4];
#pragma unroll
            for (int r = 0; r < 4; ++r) {
                const float sel = (kv == vq[r]) ? as_ : ac_;
                p[r] = exp2f(fmaf(sc[r], SCL2, sel));
                li[r] += p[r];
            }
            const unsigned p01 = pk_bf16(p[0], p[1]);
            const unsigned p23 = pk_bf16(p[2], p[3]);
            u16* pb = &pls[w][quad * 4][nt * 16 + l16];
            pb[0]       = (u16)p01;  pb[72]      = (u16)(p01 >> 16);
            pb[2 * 72]  = (u16)p23;  pb[3 * 72]  = (u16)(p23 >> 16);
        }

        const bf16x8 ap0 = *(const bf16x8*)&pls[w][l16][quad * 8];
        const bf16x8 ap1 = *(const bf16x8*)&pls[w][l16][32 + quad * 8];

        // ---- O += P @ V (no rescale) ----
#pragma unroll
        for (int nt = 0; nt < 4; ++nt) {
            const int vrow = nt * 16 + l16;
            const int r7   = vrow & 7;
            const bf16x8 vb0 = *(const bf16x8*)&vbuf[cur][vrow * 64 + ((quad ^ r7) << 3)];
            const bf16x8 vb1 = *(const bf16x8*)&vbuf[cur][vrow * 64 + ((quad ^ r7 ^ 4) << 3)];
            o[nt] = MFMA(ap0, vb0, o[nt]);
            o[nt] = MFMA(ap1, vb1, o[nt]);
        }
    };

    stage(0, 0);
    for (int kt = 0; kt < NKT; kt += 2) {
        __syncthreads();                    // buffer0 staged; everyone done with buffer1
        stage(kt + 1, 1);
        body(0);
        __syncthreads();                    // buffer1 staged; everyone done with buffer0
        if (kt + 2 < NKT) stage(kt + 2, 0);
        body(1);
    }

    // ---- epilogue: reduce li across the quad-row group, normalize, write ----
#pragma unroll
    for (int r = 0; r < 4; ++r) {
        const float inv = 1.0f / qsum16(li[r]);
        const int R = q0 + w * 16 + quad * 4 + r;
        const int rb = (b * SEQ + R) * DMODEL + h * HEADDIM;
#pragma unroll
        for (int nt = 0; nt < 4; ++nt)
            attn[rb + nt * 16 + l16] = f2bf(o[nt][r] * inv);
    }
}

// ---------------- kernel 3: output projection (128x128, LDS-staged, fp32 out) ----------------
__global__ __launch_bounds__(256) void proj_kernel(
    const u16* __restrict__ a, const u16* __restrict__ Wo,
    const float* __restrict__ bo, float* __restrict__ out)
{
    __shared__ alignas(16) u16 As[128 * 64];
    __shared__ alignas(16) u16 Bs[128 * 64];

    const int m0 = blockIdx.x * 128;
    const int n0 = blockIdx.y * 128;         // [0,512)
    const int tid  = threadIdx.x;
    const int w    = tid >> 6;
    const int lane = tid & 63;
    const int quad = lane >> 4;
    const int l16  = lane & 15;
    const int wm = w & 1, wn = w >> 1;

    f32x4 acc[4][4] = {};

    for (int kb = 0; kb < 8; ++kb) {
#pragma unroll
        for (int it = 0; it < 4; ++it) {
            const int s   = it * 256 + tid;
            const int row = s >> 3;
            const int cb  = s & 7;
            const int gcol = kb * 64 + (((cb ^ (row & 7))) << 3);
            gll16(a  + (m0 + row) * 512 + gcol, &As[s * 8]);
            gll16(Wo + (n0 + row) * 512 + gcol, &Bs[s * 8]);
        }
        __syncthreads();

#pragma unroll
        for (int ks = 0; ks < 2; ++ks) {
            bf16x8 av[4], bv[4];
#pragma unroll
            for (int t = 0; t < 4; ++t) {
                const int arow = wm * 64 + t * 16 + l16;
                av[t] = *(const bf16x8*)&As[arow * 64 + (((ks * 4 + quad) ^ (arow & 7)) << 3)];
                const int brow = wn * 64 + t * 16 + l16;
                bv[t] = *(const bf16x8*)&Bs[brow * 64 + (((ks * 4 + quad) ^ (brow & 7)) << 3)];
            }
#pragma unroll
            for (int tm = 0; tm < 4; ++tm)
#pragma unroll
                for (int tn = 0; tn < 4; ++tn)
                    acc[tm][tn] = MFMA(av[tm], bv[tn], acc[tm][tn]);
        }
        __syncthreads();
    }

#pragma unroll
    for (int tm = 0; tm < 4; ++tm) {
#pragma unroll
        for (int tn = 0; tn < 4; ++tn) {
            const int col = n0 + wn * 64 + tn * 16 + l16;
            const float bval = bo[col];
#pragma unroll
            for (int r = 0; r < 4; ++r) {
                const int R = m0 + wm * 64 + tm * 16 + quad * 4 + r;
                out[R * 512 + col] = acc[tm][tn][r] + bval;
            }
        }
    }
}

// ---------------- launch ----------------
extern "C" void kernel_launch(void* const* d_in, const int* in_sizes, int n_in,
                              void* d_out, int out_size, void* d_ws, size_t ws_size,
                              hipStream_t stream) {
    const float* x    = (const float*)d_in[0];
    const int*   vids = (const int*)d_in[1];
    const float* mask = (const float*)d_in[2];
    const float* Wq = (const float*)d_in[3];
    const float* bq = (const float*)d_in[4];
    const float* Wk = (const float*)d_in[5];
    const float* bk = (const float*)d_in[6];
    const float* Wv = (const float*)d_in[7];
    const float* bv = (const float*)d_in[8];
    const float* Wo = (const float*)d_in[9];
    const float* bo = (const float*)d_in[10];
    const float* usame  = (const float*)d_in[11];
    const float* ucross = (const float*)d_in[12];
    float* out = (float*)d_out;

    // workspace layout (~35 MB total)
    u16* xbf  = (u16*)d_ws;                 // 8 MB; reused as attention output
    u16* wqbf = xbf + NX;                   // 512 KB each
    u16* wkbf = wqbf + NW;
    u16* wvbf = wkbf + NW;
    u16* wobf = wvbf + NW;
    float2* cst = (float2*)(wobf + NW);     // 512 KB (2048 x 32 float2)
    u16* qws  = (u16*)(cst + SEQ * 32);     // 8 MB each
    u16* kws  = qws + (size_t)BATCH * NHEADS * SEQ * HEADDIM;
    u16* vtws = kws + (size_t)BATCH * NHEADS * SEQ * HEADDIM;
    u16* attn = xbf;   // reuse: qkv_kernel has finished with xbf before attn writes

    cvt_rope_kernel<<<(NCVT4 + SEQ * 32 / 4 + 255) / 256, 256, 0, stream>>>(
        x, Wq, Wk, Wv, Wo, xbf, wqbf, wkbf, wvbf, wobf, cst);

    dim3 g1(MTOT / 128, 3 * DMODEL / 128);  // 64 x 12
    qkv_kernel<<<g1, 256, 0, stream>>>(xbf, wqbf, bq, wkbf, bk, wvbf, bv,
                                       cst, qws, kws, vtws);

    dim3 g2(SEQ / QTILE, BATCH * NHEADS);   // 16 x 32
    attn_kernel<<<g2, 512, 0, stream>>>(qws, kws, vtws, vids, mask,
                                        usame, ucross, attn);

    dim3 g3(MTOT / 128, DMODEL / 128);      // 64 x 4
    proj_kernel<<<g3, 256, 0, stream>>>(attn, wobf, bo, out);
}